// Round 1
// baseline (204.205 us; speedup 1.0000x reference)
//
#include <hip/hip_runtime.h>

#define N_NODES 100000
#define K_DEG   16
#define D_FEAT  128   // 32 float4 per row

// 32 lanes per node; lane l handles float4 at column l.
__global__ __launch_bounds__(256) void TMessagePassing_kernel(
    const float* __restrict__ x,
    const int*   __restrict__ nbr,
    float*       __restrict__ out)
{
    int gid  = blockIdx.x * blockDim.x + threadIdx.x;
    int v    = gid >> 5;        // node index
    int col  = gid & 31;        // float4 column within the 128-float row
    if (v >= N_NODES) return;

    const float4* __restrict__ x4 = (const float4*)x;

    float4 s1 = make_float4(0.f, 0.f, 0.f, 0.f);   // sum x_u
    float4 s2 = make_float4(0.f, 0.f, 0.f, 0.f);   // sum x_u^2

    const int* __restrict__ nrow = nbr + (size_t)v * K_DEG;

#pragma unroll
    for (int k = 0; k < K_DEG; ++k) {
        int u = nrow[k];
        float4 xu = x4[(size_t)u * (D_FEAT / 4) + col];
        s1.x += xu.x; s1.y += xu.y; s1.z += xu.z; s1.w += xu.w;
        s2.x += xu.x * xu.x; s2.y += xu.y * xu.y;
        s2.z += xu.z * xu.z; s2.w += xu.w * xu.w;
    }

    float4 xv = x4[(size_t)v * (D_FEAT / 4) + col];

    const float coef = 1.0f / 48.0f;   // (2/6)/K
    float4 o;
    o.x = coef * (2.f * xv.x * s1.x + s2.x);
    o.y = coef * (2.f * xv.y * s1.y + s2.y);
    o.z = coef * (2.f * xv.z * s1.z + s2.z);
    o.w = coef * (2.f * xv.w * s1.w + s2.w);

    ((float4*)out)[(size_t)v * (D_FEAT / 4) + col] = o;
}

extern "C" void kernel_launch(void* const* d_in, const int* in_sizes, int n_in,
                              void* d_out, int out_size, void* d_ws, size_t ws_size,
                              hipStream_t stream) {
    const float* x   = (const float*)d_in[0];
    const int*   nbr = (const int*)d_in[1];
    float*       out = (float*)d_out;

    // 32 threads per node, 256 threads per block -> 8 nodes/block
    int total_threads = N_NODES * 32;
    int block = 256;
    int grid  = (total_threads + block - 1) / block;   // 12500
    TMessagePassing_kernel<<<grid, block, 0, stream>>>(x, nbr, out);
}

// Round 2
// 201.611 us; speedup vs baseline: 1.0129x; 1.0129x over previous
//
#include <hip/hip_runtime.h>

#define N_NODES 100000
#define K_DEG   16
#define D_FEAT  128   // 32 float4 per row

// 32 lanes per node; lane l handles float4 column l.
// Key change vs R0: load all 16 neighbor indices up front (4x int4), then
// issue all 16 gathers before accumulating -> 16 loads in flight per lane.
__global__ __launch_bounds__(256, 4) void TMessagePassing_kernel(
    const float* __restrict__ x,
    const int*   __restrict__ nbr,
    float*       __restrict__ out)
{
    int gid = blockIdx.x * blockDim.x + threadIdx.x;
    int v   = gid >> 5;
    int col = gid & 31;

    const float4* __restrict__ x4 = (const float4*)x;

    // Load the 16 neighbor indices as 4 x int4 (all 32 lanes of this node
    // read the same 64B -> broadcast). One dependency barrier, not 16.
    const int4* __restrict__ nb4 = (const int4*)(nbr + (size_t)v * K_DEG);
    int4 n0 = nb4[0];
    int4 n1 = nb4[1];
    int4 n2 = nb4[2];
    int4 n3 = nb4[3];

    int idx[K_DEG] = { n0.x, n0.y, n0.z, n0.w,
                       n1.x, n1.y, n1.z, n1.w,
                       n2.x, n2.y, n2.z, n2.w,
                       n3.x, n3.y, n3.z, n3.w };

    // Own row (issued alongside the gathers).
    float4 xv = x4[(size_t)v * (D_FEAT / 4) + col];

    // Issue ALL gathers first -> compiler drains with staged vmcnt(N).
    float4 xu[K_DEG];
#pragma unroll
    for (int k = 0; k < K_DEG; ++k) {
        xu[k] = x4[(size_t)idx[k] * (D_FEAT / 4) + col];
    }

    float4 s1 = make_float4(0.f, 0.f, 0.f, 0.f);
    float4 s2 = make_float4(0.f, 0.f, 0.f, 0.f);
#pragma unroll
    for (int k = 0; k < K_DEG; ++k) {
        float4 u = xu[k];
        s1.x += u.x; s1.y += u.y; s1.z += u.z; s1.w += u.w;
        s2.x += u.x * u.x; s2.y += u.y * u.y;
        s2.z += u.z * u.z; s2.w += u.w * u.w;
    }

    const float coef = 1.0f / 48.0f;   // (2/6)/K
    float4 o;
    o.x = coef * (2.f * xv.x * s1.x + s2.x);
    o.y = coef * (2.f * xv.y * s1.y + s2.y);
    o.z = coef * (2.f * xv.z * s1.z + s2.z);
    o.w = coef * (2.f * xv.w * s1.w + s2.w);

    ((float4*)out)[(size_t)v * (D_FEAT / 4) + col] = o;
}

extern "C" void kernel_launch(void* const* d_in, const int* in_sizes, int n_in,
                              void* d_out, int out_size, void* d_ws, size_t ws_size,
                              hipStream_t stream) {
    const float* x   = (const float*)d_in[0];
    const int*   nbr = (const int*)d_in[1];
    float*       out = (float*)d_out;

    int total_threads = N_NODES * 32;           // 3,200,000 -> exact multiple of 256
    int block = 256;
    int grid  = (total_threads + block - 1) / block;   // 12500
    TMessagePassing_kernel<<<grid, block, 0, stream>>>(x, nbr, out);
}